// Round 6
// baseline (651.894 us; speedup 1.0000x reference)
//
#include <hip/hip_runtime.h>

#define HH_EPS 1e-8f

constexpr int D     = 2048;            // feature dim
constexpr int K     = 16;              // number of reflections
constexpr int CH    = D / (64 * 4);    // 8 float4 chunks per lane per row
constexpr int NROWS = 4 * 4096;        // B * S = 16384
constexpr int WPB   = 4;               // waves per block (256 threads)

// ---------------------------------------------------------------------------
// Kernel 1: Gram matrix G[i][j] = v_i . v_j  (one wave per (i,j) pair).
// ---------------------------------------------------------------------------
__global__ void __launch_bounds__(64) hh_gram_kernel(const float* __restrict__ vecs,
                                                     float* __restrict__ G) {
    int i = blockIdx.x >> 4, j = blockIdx.x & 15;
    int lane = threadIdx.x;
    const float4* a = (const float4*)(vecs + i * D);
    const float4* b = (const float4*)(vecs + j * D);
    float s = 0.f;
#pragma unroll
    for (int c = 0; c < CH; ++c) {
        float4 x = a[c * 64 + lane], y = b[c * 64 + lane];
        s += x.x * y.x + x.y * y.y + x.z * y.z + x.w * y.w;
    }
#pragma unroll
    for (int off = 32; off >= 1; off >>= 1) s += __shfl_xor(s, off);
    if (lane == 0) G[i * K + j] = s;
}

// ---------------------------------------------------------------------------
// Kernel 2: build T (upper triangular): H0..H15 = I - V T V^T (larft).
//   T[k][k] = beta_k = 2 / max(G[k][k], EPS)
//   T[i][k] = -beta_k * sum_{j=i}^{k-1} T[i][j] * G[j][k]   (i < k)
// ---------------------------------------------------------------------------
__global__ void __launch_bounds__(256) hh_buildT_kernel(const float* __restrict__ G,
                                                        float* __restrict__ T) {
    __shared__ float sG[K * K], sT[K * K];
    int t = threadIdx.x;
    sG[t] = G[t]; sT[t] = 0.f;
    __syncthreads();
    for (int k = 0; k < K; ++k) {
        float beta = 2.f / fmaxf(sG[k * K + k], HH_EPS);
        if (t == k) sT[k * K + k] = beta;
        else if (t < k) {
            float s = 0.f;
            for (int j = t; j < k; ++j) s += sT[t * K + j] * sG[j * K + k];
            sT[t * K + k] = -beta * s;
        }
        __syncthreads();
    }
    T[t] = sT[t];
}

// ---------------------------------------------------------------------------
// WY dot phase: P[k] partials for one k from h (regs) x v_cur (regs), while
// prefetching v_knext into the other buffer. 4 accumulators per row keep the
// FMA dependence chains at depth 8.
// ---------------------------------------------------------------------------
__device__ __forceinline__ void wy_dot_phase(const float4 (&h0)[CH], const float4 (&h1)[CH],
                                             const float4 (&vc)[CH], float4 (&vn)[CH],
                                             const float4* __restrict__ v4,
                                             int knext, int lane,
                                             float& P0k, float& P1k) {
#pragma unroll
    for (int j = 0; j < CH; ++j)
        vn[j] = v4[knext * (D / 4) + j * 64 + lane];
    float ax = 0.f, ay = 0.f, az = 0.f, aw = 0.f;
    float bx = 0.f, by = 0.f, bz = 0.f, bw = 0.f;
#pragma unroll
    for (int j = 0; j < CH; ++j) {
        ax += h0[j].x * vc[j].x; ay += h0[j].y * vc[j].y;
        az += h0[j].z * vc[j].z; aw += h0[j].w * vc[j].w;
        bx += h1[j].x * vc[j].x; by += h1[j].y * vc[j].y;
        bz += h1[j].z * vc[j].z; bw += h1[j].w * vc[j].w;
    }
    P0k = (ax + ay) + (az + aw);
    P1k = (bx + by) + (bz + bw);
    __builtin_amdgcn_sched_barrier(0);   // keep prefetch depth at exactly 1 phase
}

// ---------------------------------------------------------------------------
// WY update phase: h -= w_k * v_k (regs), prefetching v_knext.
// ---------------------------------------------------------------------------
__device__ __forceinline__ void wy_upd_phase(float4 (&h0)[CH], float4 (&h1)[CH],
                                             const float4 (&vc)[CH], float4 (&vn)[CH],
                                             const float4* __restrict__ v4,
                                             int knext, int lane,
                                             float w0, float w1) {
#pragma unroll
    for (int j = 0; j < CH; ++j)
        vn[j] = v4[knext * (D / 4) + j * 64 + lane];
#pragma unroll
    for (int j = 0; j < CH; ++j) {
        h0[j].x -= w0 * vc[j].x; h0[j].y -= w0 * vc[j].y;
        h0[j].z -= w0 * vc[j].z; h0[j].w -= w0 * vc[j].w;
        h1[j].x -= w1 * vc[j].x; h1[j].y -= w1 * vc[j].y;
        h1[j].z -= w1 * vc[j].z; h1[j].w -= w1 * vc[j].w;
    }
    __builtin_amdgcn_sched_barrier(0);
}

// ---------------------------------------------------------------------------
// Apply kernel: compact-WY in Round-0's structure — NO LDS staging of V, NO
// barriers in the hot path, h[2][8] register-resident load-to-store (read
// once, written once). V streams from L1/L2 (128 KB, shared by all CUs)
// through the va/vb double-buffer, twice. All k-indexing is compile-time
// (full unroll) so no array ever sees a runtime index (rule #20).
// R0 proved this shape runs spill-free at (256,2): WRITE was exactly 128 MiB.
// ---------------------------------------------------------------------------
__global__ void __launch_bounds__(256, 2)
hh_apply_wy(const float* __restrict__ h_in, const float* __restrict__ vecs,
            const float* __restrict__ Tmat, float* __restrict__ h_out) {
    __shared__ float sT[K * K];          // 1 KB: T only

    const int t    = threadIdx.x;
    const int lane = t & 63;
    const int gw   = blockIdx.x * WPB + (t >> 6);
    const size_t rbase = (size_t)gw * 2;          // 2 rows per wave

    const float4* r0 = (const float4*)h_in + rbase * (D / 4);
    const float4* r1 = r0 + (D / 4);

    // Issue h loads first; their latency hides under v0-load + sT + barrier.
    float4 h0[CH], h1[CH];
#pragma unroll
    for (int j = 0; j < CH; ++j) { h0[j] = r0[j * 64 + lane]; h1[j] = r1[j * 64 + lane]; }

    const float4* v4 = (const float4*)vecs;
    float4 va[CH], vb[CH];
#pragma unroll
    for (int j = 0; j < CH; ++j) va[j] = v4[j * 64 + lane];   // v_0

    sT[t] = Tmat[t];
    __syncthreads();   // prologue only; no barriers after this point

    // ---- dot pass: 16 independent phases, va/vb rotation ---------------
    // Phase k prefetches v_{k+1}; at k=14 the "k+2" prefetch wraps to v_0,
    // leaving va = v_0 ready for the update pass.
    float P0[K], P1[K];
#pragma unroll
    for (int k = 0; k < K; k += 2) {
        wy_dot_phase(h0, h1, va, vb, v4, (k + 1) & 15, lane, P0[k], P1[k]);
        wy_dot_phase(h0, h1, vb, va, v4, (k + 2) & 15, lane, P0[k + 1], P1[k + 1]);
    }

    // ---- butterfly reduce, split P0 then P1 to bound temp liveness -----
#pragma unroll
    for (int off = 32; off >= 1; off >>= 1)
#pragma unroll
        for (int k = 0; k < K; ++k) P0[k] += __shfl_xor(P0[k], off);
    __builtin_amdgcn_sched_barrier(0);
#pragma unroll
    for (int off = 32; off >= 1; off >>= 1)
#pragma unroll
        for (int k = 0; k < K; ++k) P1[k] += __shfl_xor(P1[k], off);

    // ---- w = p . T, in place (upper triangular; descending j safe) -----
#pragma unroll
    for (int j = K - 1; j >= 0; --j) {
        float s0 = 0.f, s1 = 0.f;
#pragma unroll
        for (int k = 0; k <= j; ++k) {
            float tk = sT[k * K + j];   // uniform addr -> LDS broadcast
            s0 += P0[k] * tk;
            s1 += P1[k] * tk;
        }
        P0[j] = s0; P1[j] = s1;
    }

    // ---- update pass: h -= sum_k w_k v_k, same rotation (va holds v_0) -
#pragma unroll
    for (int k = 0; k < K; k += 2) {
        wy_upd_phase(h0, h1, va, vb, v4, (k + 1) & 15, lane, P0[k], P1[k]);
        wy_upd_phase(h0, h1, vb, va, v4, (k + 2) & 15, lane, P0[k + 1], P1[k + 1]);
    }

    // ---- store (h never touched global between load and here) ----------
    float4* o0 = (float4*)h_out + rbase * (D / 4);
    float4* o1 = o0 + (D / 4);
#pragma unroll
    for (int j = 0; j < CH; ++j) { o0[j * 64 + lane] = h0[j]; o1[j * 64 + lane] = h1[j]; }
}

extern "C" void kernel_launch(void* const* d_in, const int* in_sizes, int n_in,
                              void* d_out, int out_size, void* d_ws, size_t ws_size,
                              hipStream_t stream) {
    const float* h    = (const float*)d_in[0];   // [4,4096,2048] fp32
    const float* vecs = (const float*)d_in[1];   // [16,2048] fp32
    float* out        = (float*)d_out;           // [4,4096,2048] fp32

    float* G  = (float*)d_ws;                    // 256 floats
    float* Tm = G + K * K;                       // 256 floats

    hh_gram_kernel<<<K * K, 64, 0, stream>>>(vecs, G);
    hh_buildT_kernel<<<1, 256, 0, stream>>>(G, Tm);

    int blocks = NROWS / (2 * WPB);              // 2048 blocks of 4 waves
    hh_apply_wy<<<blocks, 256, 0, stream>>>(h, vecs, Tm, out);
}

// Round 7
// 264.893 us; speedup vs baseline: 2.4610x; 2.4610x over previous
//
#include <hip/hip_runtime.h>

#define HH_EPS 1e-8f

constexpr int D     = 2048;            // feature dim
constexpr int K     = 16;              // number of reflections
constexpr int RR    = 4;               // rows per wave (R0's proven shape)
constexpr int CH    = D / (64 * 4);    // 8 float4 chunks per lane per row
constexpr int NROWS = 4 * 4096;        // B * S = 16384
constexpr int WPB   = 4;               // waves per block (256 threads)
constexpr int SPAD  = 65;              // padded lane stride (2-way conflicts only)

// ---------------------------------------------------------------------------
// Kernel 1: Gram matrix G[i][j] = v_i . v_j  (one wave per (i,j) pair).
// ---------------------------------------------------------------------------
__global__ void __launch_bounds__(64) hh_gram_kernel(const float* __restrict__ vecs,
                                                     float* __restrict__ G) {
    int i = blockIdx.x >> 4, j = blockIdx.x & 15;
    int lane = threadIdx.x;
    const float4* a = (const float4*)(vecs + i * D);
    const float4* b = (const float4*)(vecs + j * D);
    float s = 0.f;
#pragma unroll
    for (int c = 0; c < CH; ++c) {
        float4 x = a[c * 64 + lane], y = b[c * 64 + lane];
        s += x.x * y.x + x.y * y.y + x.z * y.z + x.w * y.w;
    }
#pragma unroll
    for (int off = 32; off >= 1; off >>= 1) s += __shfl_xor(s, off);
    if (lane == 0) G[i * K + j] = s;
}

// ---------------------------------------------------------------------------
// Kernel 2: build T (upper triangular): H0..H15 = I - V T V^T (larft).
//   T[k][k] = beta_k = 2 / max(G[k][k], EPS)
//   T[i][k] = -beta_k * sum_{j=i}^{k-1} T[i][j] * G[j][k]   (i < k)
// Lower triangle stays 0 (required: apply kernel sums over all k).
// ---------------------------------------------------------------------------
__global__ void __launch_bounds__(256) hh_buildT_kernel(const float* __restrict__ G,
                                                        float* __restrict__ T) {
    __shared__ float sG[K * K], sT[K * K];
    int t = threadIdx.x;
    sG[t] = G[t]; sT[t] = 0.f;
    __syncthreads();
    for (int k = 0; k < K; ++k) {
        float beta = 2.f / fmaxf(sG[k * K + k], HH_EPS);
        if (t == k) sT[k * K + k] = beta;
        else if (t < k) {
            float s = 0.f;
            for (int j = t; j < k; ++j) s += sT[t * K + j] * sG[j * K + k];
            sT[t * K + k] = -beta * s;
        }
        __syncthreads();
    }
    T[t] = sT[t];
}

// ---------------------------------------------------------------------------
// Dot phase k: per-lane partials for 4 rows -> straight to per-wave LDS
// (no cross-phase register state). Prefetches v_{knext} into vn.
// ---------------------------------------------------------------------------
__device__ __forceinline__ void wy_dot_phase(const float4 (&h)[RR][CH],
                                             const float4 (&vc)[CH], float4 (&vn)[CH],
                                             const float4* __restrict__ v4,
                                             int knext, int lane,
                                             float* __restrict__ myP, int k) {
#pragma unroll
    for (int j = 0; j < CH; ++j)
        vn[j] = v4[knext * (D / 4) + j * 64 + lane];
#pragma unroll
    for (int r = 0; r < RR; ++r) {
        float ax = 0.f, ay = 0.f, az = 0.f, aw = 0.f;
#pragma unroll
        for (int j = 0; j < CH; ++j) {
            ax += h[r][j].x * vc[j].x; ay += h[r][j].y * vc[j].y;
            az += h[r][j].z * vc[j].z; aw += h[r][j].w * vc[j].w;
        }
        myP[(r * K + k) * SPAD + lane] = (ax + ay) + (az + aw);
    }
}

// ---------------------------------------------------------------------------
// Update phase k: h[r] -= w_r[k] * v_k; w read as uniform LDS broadcast.
// ---------------------------------------------------------------------------
__device__ __forceinline__ void wy_upd_phase(float4 (&h)[RR][CH],
                                             const float4 (&vc)[CH], float4 (&vn)[CH],
                                             const float4* __restrict__ v4,
                                             int knext, int lane,
                                             const float* __restrict__ myW, int k) {
#pragma unroll
    for (int j = 0; j < CH; ++j)
        vn[j] = v4[knext * (D / 4) + j * 64 + lane];
#pragma unroll
    for (int r = 0; r < RR; ++r) {
        const float w = myW[r * K + k];    // uniform address -> LDS broadcast
#pragma unroll
        for (int j = 0; j < CH; ++j) {
            h[r][j].x -= w * vc[j].x; h[r][j].y -= w * vc[j].y;
            h[r][j].z -= w * vc[j].z; h[r][j].w -= w * vc[j].w;
        }
    }
}

// ---------------------------------------------------------------------------
// Apply kernel: compact-WY with Round-0's exact register profile.
// h[4][8] register-resident load-to-store; va/vb double-buffer from L2;
// runtime (#pragma unroll 1) k-loops; NO sched_barriers; NO register P
// arrays — per-phase partials live in per-wave LDS, reduced once by a
// padded transpose-read + 2 shuffles. sP/sD/sW are wave-private: no
// __syncthreads after the prologue (same-wave lgkmcnt orders LDS).
// ---------------------------------------------------------------------------
__global__ void __launch_bounds__(256, 2)
hh_apply_wy(const float* __restrict__ h_in, const float* __restrict__ vecs,
            const float* __restrict__ Tmat, float* __restrict__ h_out) {
    __shared__ float sP[WPB * RR * K * SPAD];   // 65 KB: per-wave partials
    __shared__ float sD[WPB * RR * K];          // 1 KB: reduced dots
    __shared__ float sW[WPB * RR * K];          // 1 KB: w = P.T
    __shared__ float sT[K * K];                 // 1 KB

    const int t    = threadIdx.x;
    const int wv   = t >> 6;
    const int lane = t & 63;
    const int gw   = blockIdx.x * WPB + wv;
    const size_t rbase = (size_t)gw * RR;

    // h rows into registers (issued first; latency hides under v0 + sT).
    float4 h[RR][CH];
    const float4* hin4 = (const float4*)h_in;
#pragma unroll
    for (int r = 0; r < RR; ++r)
#pragma unroll
        for (int j = 0; j < CH; ++j)
            h[r][j] = hin4[(rbase + r) * (D / 4) + j * 64 + lane];

    const float4* v4 = (const float4*)vecs;
    float4 va[CH], vb[CH];
#pragma unroll
    for (int j = 0; j < CH; ++j) va[j] = v4[j * 64 + lane];   // v_0

    sT[t] = Tmat[t];
    __syncthreads();   // sT is block-shared; only barrier in the kernel

    float* myP = sP + wv * (RR * K * SPAD);
    float* myD = sD + wv * (RR * K);
    float* myW = sW + wv * (RR * K);

    // ---- dot pass: 16 independent phases, va/vb rotation ---------------
#pragma unroll 1
    for (int k = 0; k < K; k += 2) {
        wy_dot_phase(h, va, vb, v4, (k + 1) & 15, lane, myP, k);
        wy_dot_phase(h, vb, va, v4, (k + 2) & 15, lane, myP, k + 1);
    }
    // after wrap, va holds v_0 again for the update pass

    // ---- transpose-reduce: lane l -> k=l&15, segment l>>4 ---------------
    // read banks: (k*65 + seg*16 + i) % 32 -> 2-way worst case (free).
    const int kk  = lane & 15;
    const int seg = lane >> 4;
#pragma unroll
    for (int r = 0; r < RR; ++r) {
        float s = 0.f;
#pragma unroll
        for (int i = 0; i < 16; ++i)
            s += myP[(r * K + kk) * SPAD + seg * 16 + i];
        s += __shfl_xor(s, 16);
        s += __shfl_xor(s, 32);
        if (lane < 16) myD[r * K + kk] = s;
    }

    // ---- w[j] = sum_k P[k] * T[k][j] (lower triangle of T is 0) --------
#pragma unroll
    for (int r = 0; r < RR; ++r) {
        float wsum = 0.f;
#pragma unroll
        for (int k2 = 0; k2 < K; ++k2)
            wsum += myD[r * K + k2] * sT[k2 * K + kk];   // myD uniform-bcast
        if (lane < 16) myW[r * K + kk] = wsum;
    }

    // ---- update pass: h -= sum_k w_k v_k, same va/vb rotation ----------
#pragma unroll 1
    for (int k = 0; k < K; k += 2) {
        wy_upd_phase(h, va, vb, v4, (k + 1) & 15, lane, myW, k);
        wy_upd_phase(h, vb, va, v4, (k + 2) & 15, lane, myW, k + 1);
    }

    // ---- store (h untouched in global between load and here) -----------
#pragma unroll
    for (int r = 0; r < RR; ++r) {
        float4* row = (float4*)h_out + (rbase + r) * (D / 4);
#pragma unroll
        for (int j = 0; j < CH; ++j)
            row[j * 64 + lane] = h[r][j];
    }
}

extern "C" void kernel_launch(void* const* d_in, const int* in_sizes, int n_in,
                              void* d_out, int out_size, void* d_ws, size_t ws_size,
                              hipStream_t stream) {
    const float* h    = (const float*)d_in[0];   // [4,4096,2048] fp32
    const float* vecs = (const float*)d_in[1];   // [16,2048] fp32
    float* out        = (float*)d_out;           // [4,4096,2048] fp32

    float* G  = (float*)d_ws;                    // 256 floats
    float* Tm = G + K * K;                       // 256 floats

    hh_gram_kernel<<<K * K, 64, 0, stream>>>(vecs, G);
    hh_buildT_kernel<<<1, 256, 0, stream>>>(G, Tm);

    int blocks = NROWS / (RR * WPB);             // 1024 blocks of 4 waves
    hh_apply_wy<<<blocks, 256, 0, stream>>>(h, vecs, Tm, out);
}